// Round 7
// baseline (550.481 us; speedup 1.0000x reference)
//
#include <hip/hip_runtime.h>
#include <hip/hip_bf16.h>

#define SEQ 4096
#define DIMC 2048
#define NH 16
#define DHD 128

typedef short s8v __attribute__((ext_vector_type(8)));
typedef float f4v __attribute__((ext_vector_type(4)));
typedef __bf16 bf8 __attribute__((ext_vector_type(8)));
typedef float f4 __attribute__((ext_vector_type(4)));
typedef float f16v __attribute__((ext_vector_type(16)));
typedef int i4v __attribute__((ext_vector_type(4)));

typedef __attribute__((address_space(3))) void lds_t;
typedef __attribute__((address_space(1))) void gbl_t;

// Static device scratch (112 MiB). No d_ws dependence.
__device__ __attribute__((aligned(256))) short g_h[(size_t)SEQ * DIMC];
__device__ __attribute__((aligned(256))) short g_q[(size_t)SEQ * DIMC];
__device__ __attribute__((aligned(256))) short g_k[(size_t)SEQ * DIMC];
__device__ __attribute__((aligned(256))) short g_v[(size_t)SEQ * DIMC];
__device__ __attribute__((aligned(256))) short g_vt[(size_t)DIMC * SEQ];     // [h*128+d][s]
__device__ __attribute__((aligned(256))) short g_wt[4][(size_t)DIMC * DIMC]; // [n][k]

__device__ __forceinline__ float b2f(short s) {
    union { unsigned u; float f; } v;
    v.u = ((unsigned)(unsigned short)s) << 16;
    return v.f;
}
__device__ __forceinline__ short f2b(float f) {
    union { float f; unsigned u; } v;
    v.f = f;
    unsigned b = v.u;
    b += 0x7FFFu + ((b >> 16) & 1u);   // RNE
    return (short)(b >> 16);
}
__device__ __forceinline__ f4 mfma16(bf8 a, bf8 b, f4 c) {
    return __builtin_amdgcn_mfma_f32_16x16x32_bf16(a, b, c, 0, 0, 0);
}
__device__ __forceinline__ f16v mfma32(bf8 a, bf8 b, f16v c) {
    return __builtin_amdgcn_mfma_f32_32x32x16_bf16(a, b, c, 0, 0, 0);
}
__device__ __forceinline__ void gl_lds16(const short* g, short* l) {
    __builtin_amdgcn_global_load_lds((gbl_t*)g, (lds_t*)l, 16, 0, 0);
}
// v_permlane32_swap_b32: a' = [a_lo, b_lo], b' = [a_hi, b_hi] (32-lane halves)
__device__ __forceinline__ void plane32_swap(int& a, int& b) {
    asm("v_permlane32_swap_b32 %0, %1" : "+v"(a), "+v"(b));
}
// packed f32 pair -> one u32 of 2x bf16 (RNE), T12 recipe (no builtin on gfx950)
__device__ __forceinline__ int pk2b(float a, float b) {
    int r;
    asm("v_cvt_pk_bf16_f32 %0, %1, %2" : "=v"(r) : "v"(a), "v"(b));
    return r;
}
// raw v_exp_f32 (2^x) — skips OCML denormal fixup.
__device__ __forceinline__ float fexp2(float x) {
#if __has_builtin(__builtin_amdgcn_exp2f)
    return __builtin_amdgcn_exp2f(x);
#else
    float r;
    asm("v_exp_f32 %0, %1" : "=v"(r) : "v"(x));
    return r;
#endif
}

// ---------------- hidden f32 -> g_h bf16 ----------------
__global__ __launch_bounds__(256) void conv_h(const float* __restrict__ src) {
    size_t i = ((size_t)blockIdx.x * 256 + threadIdx.x) * 8;
    f4v u0 = *reinterpret_cast<const f4v*>(src + i);
    f4v u1 = *reinterpret_cast<const f4v*>(src + i + 4);
    s8v t;
    for (int j = 0; j < 4; ++j) { t[j] = f2b(u0[j]); t[4 + j] = f2b(u1[j]); }
    *reinterpret_cast<s8v*>(g_h + i) = t;
}

// ---------------- W f32 [k][n] -> g_wt[z] bf16 [n][k] ----------------
__global__ __launch_bounds__(256) void prep_w(const float* __restrict__ W0,
                                              const float* __restrict__ W1,
                                              const float* __restrict__ W2,
                                              const float* __restrict__ W3) {
    __shared__ __attribute__((aligned(16))) float t[64][64];
    const int z = blockIdx.z;
    const float* W = (z == 0) ? W0 : (z == 1) ? W1 : (z == 2) ? W2 : W3;
    short* WT = g_wt[z];
    const int r0 = blockIdx.y * 64, c0 = blockIdx.x * 64;   // r=k, c=n
    const int tid = threadIdx.x;
    for (int i = 0; i < 4; ++i) {
        int slot = tid + i * 256;
        int r = slot >> 4, c4 = (slot & 15) * 4;
        int pb = ((c4 >> 3) + (r >> 3)) & 7;                // rotated phys block
        *reinterpret_cast<f4v*>(&t[r][pb * 8 + (c4 & 7)]) =
            *reinterpret_cast<const f4v*>(&W[(size_t)(r0 + r) * DIMC + c0 + c4]);
    }
    __syncthreads();
    for (int i = 0; i < 2; ++i) {
        int slot = tid + i * 256;
        int n = slot >> 3, k8 = (slot & 7) * 8;
        int pb = ((n >> 3) + (slot & 7)) & 7;               // row>>3 == slot&7 for all j
        s8v o;
        for (int j = 0; j < 8; ++j) o[j] = f2b(t[k8 + j][pb * 8 + (n & 7)]);
        *reinterpret_cast<s8v*>(&WT[(size_t)(c0 + n) * DIMC + r0 + k8]) = o;
    }
}

// ---------------- 8-phase pipelined GEMM (T3+T4+T2-rotation+T5) --------------
// BM=256, BN=128, BK=64, 512 threads = 8 waves (4M x 2N), per-wave C = 64x64.
// 3 LDS buffers (144 KiB): while computing K-tile t, stage tile t+2 —
// vmcnt(6) at each tile boundary keeps 6 loads in flight (never drains to 0
// in steady state). Per K-tile: 4 phases, each = {8 ds_read_b128 || 2
// global_load_lds -> barrier -> lgkmcnt(0) -> setprio(1) 8 MFMA setprio(0)
// -> barrier}. A/B tiles stored with per-row rotated 8-bf16 chunks
// (phys = (g+row)&7, pre-rotated global source): frag reads conflict-free.
template <int DSTF>
__device__ __forceinline__ void gemm8_body(const short* __restrict__ X,
                                           const short* __restrict__ Bw,
                                           const float* __restrict__ bias,
                                           short* __restrict__ Yb,
                                           float* __restrict__ Yf,
                                           int bm, int bn) {
    __shared__ __attribute__((aligned(16))) short Al[3][256 * 64];
    __shared__ __attribute__((aligned(16))) short Bl[3][128 * 64];
    const int tid = threadIdx.x;
    const int w = tid >> 6, lane = tid & 63;
    const int l16 = lane & 15, quad = lane >> 4;
    const int wm = w & 3, wn = w >> 2;

    // staging source (rotated chunks: phys chunk tid&7 holds global chunk g)
    const int row0 = tid >> 3, cp0 = tid & 7;
    const int gch = (cp0 - row0) & 7;
    const short* srcA = X + (size_t)(bm * 256 + row0) * DIMC + gch * 8;
    const short* srcB = Bw + (size_t)(bn * 128 + row0) * DIMC + gch * 8;

    // loop-invariant ds_read offsets (in shorts)
    int offA[2][2][2], offB[2][2][2];   // [q-half][frag][kh]
#pragma unroll
    for (int qh = 0; qh < 2; ++qh)
#pragma unroll
        for (int fi = 0; fi < 2; ++fi)
#pragma unroll
            for (int kh = 0; kh < 2; ++kh) {
                int g = kh * 4 + quad;
                int ra = wm * 64 + qh * 32 + fi * 16 + l16;
                offA[qh][fi][kh] = ra * 64 + (((g + ra) & 7) << 3);
                int rb = wn * 64 + qh * 32 + fi * 16 + l16;
                offB[qh][fi][kh] = rb * 64 + (((g + rb) & 7) << 3);
            }

    f4 acc[4][4];
#pragma unroll
    for (int i = 0; i < 4; ++i)
#pragma unroll
        for (int j = 0; j < 4; ++j) acc[i][j] = (f4)0.0f;

    const int NT = DIMC / 64;   // 32

    // prologue: stage tiles 0,1 (6 loads each); wait tile 0, keep tile 1 in flight
#pragma unroll
    for (int x = 0; x < 2; ++x) {
        gl_lds16(srcA,                        &Al[x][0] + tid * 8);
        gl_lds16(srcA + (size_t)64 * DIMC,    &Al[x][0] + (tid + 512) * 8);
        gl_lds16(srcA + (size_t)128 * DIMC,   &Al[x][0] + 8192 + tid * 8);
        gl_lds16(srcA + (size_t)192 * DIMC,   &Al[x][0] + 8192 + (tid + 512) * 8);
        gl_lds16(srcB,                        &Bl[x][0] + tid * 8);
        gl_lds16(srcB + (size_t)64 * DIMC,    &Bl[x][0] + (tid + 512) * 8);
        srcA += 64; srcB += 64;
    }
    asm volatile("s_waitcnt vmcnt(6)" ::: "memory");
    __builtin_amdgcn_sched_barrier(0);
    __builtin_amdgcn_s_barrier();

    int b = 0;
    for (int t = 0; t < NT; ++t) {
        const short* Ab = &Al[b][0];
        const short* Bb = &Bl[b][0];
        const int sb = (b + 2 >= 3) ? b - 1 : b + 2;
        short* dA = &Al[sb][0];
        short* dB = &Bl[sb][0];
        const bool doStage = (t + 2 < NT);

#pragma unroll
        for (int q = 0; q < 4; ++q) {
            const int qm = q & 1, qn = q >> 1;
            bf8 av[2][2], bv[2][2];
#pragma unroll
            for (int fi = 0; fi < 2; ++fi)
#pragma unroll
                for (int kh = 0; kh < 2; ++kh) {
                    av[fi][kh] = *reinterpret_cast<const bf8*>(Ab + offA[qm][fi][kh]);
                    bv[fi][kh] = *reinterpret_cast<const bf8*>(Bb + offB[qn][fi][kh]);
                }
            if (doStage) {
                if (q == 0) {
                    gl_lds16(srcA,                      dA + tid * 8);
                    gl_lds16(srcA + (size_t)64 * DIMC,  dA + (tid + 512) * 8);
                } else if (q == 1) {
                    gl_lds16(srcA + (size_t)128 * DIMC, dA + 8192 + tid * 8);
                    gl_lds16(srcA + (size_t)192 * DIMC, dA + 8192 + (tid + 512) * 8);
                } else if (q == 2) {
                    gl_lds16(srcB,                      dB + tid * 8);
                    gl_lds16(srcB + (size_t)64 * DIMC,  dB + (tid + 512) * 8);
                }
            }
            __builtin_amdgcn_s_barrier();
            asm volatile("s_waitcnt lgkmcnt(0)" ::: "memory");
            __builtin_amdgcn_sched_barrier(0);
            __builtin_amdgcn_s_setprio(1);
#pragma unroll
            for (int mi = 0; mi < 2; ++mi)
#pragma unroll
                for (int ni = 0; ni < 2; ++ni) {
                    acc[qm * 2 + mi][qn * 2 + ni] =
                        mfma16(av[mi][0], bv[ni][0], acc[qm * 2 + mi][qn * 2 + ni]);
                    acc[qm * 2 + mi][qn * 2 + ni] =
                        mfma16(av[mi][1], bv[ni][1], acc[qm * 2 + mi][qn * 2 + ni]);
                }
            __builtin_amdgcn_s_setprio(0);
            if (q == 3) {
                if (t + 1 == NT - 1) {   // next tile is last: its loads are the only ones
                    asm volatile("s_waitcnt vmcnt(0)" ::: "memory");
                } else {
                    asm volatile("s_waitcnt vmcnt(6)" ::: "memory");
                }
                __builtin_amdgcn_sched_barrier(0);
            }
            __builtin_amdgcn_s_barrier();
        }
        if (doStage) { srcA += 64; srcB += 64; }
        b = (b + 1 == 3) ? 0 : b + 1;
    }

    // epilogue: bias + store
#pragma unroll
    for (int nf = 0; nf < 4; ++nf) {
        int col = bn * 128 + wn * 64 + nf * 16 + l16;
        float bcol = bias[col];
#pragma unroll
        for (int mf = 0; mf < 4; ++mf) {
            int row = bm * 256 + wm * 64 + mf * 16 + quad * 4;
#pragma unroll
            for (int r = 0; r < 4; ++r) {
                if (DSTF)
                    Yf[(size_t)(row + r) * DIMC + col] = acc[mf][nf][r] + bcol;
                else
                    Yb[(size_t)(row + r) * DIMC + col] = f2b(acc[mf][nf][r] + bcol);
            }
        }
    }
}

__global__ __launch_bounds__(512, 2) void gemm_qkv(const float* __restrict__ bq,
                                                   const float* __restrict__ bk,
                                                   const float* __restrict__ bv) {
    const int z = blockIdx.z;
    const float* bias = (z == 0) ? bq : (z == 1) ? bk : bv;
    short* Y = (z == 0) ? g_q : (z == 1) ? g_k : g_v;
    gemm8_body<0>(g_h, g_wt[z], bias, Y, nullptr, blockIdx.y, blockIdx.x);
}

__global__ __launch_bounds__(512, 2) void gemm_o(const float* __restrict__ bias,
                                                 float* __restrict__ Yf) {
    gemm8_body<1>(g_q, g_wt[3], bias, nullptr, Yf, blockIdx.y, blockIdx.x);
}

// ---------------- fused RMSNorm + RoPE, in place on g_q/g_k ------
// q pre-scaled by log2(e)/sqrt(DHD) (folded attn scale + exp2 conversion).
__global__ __launch_bounds__(256) void rmsnorm_rope(const float* __restrict__ gq,
                                                    const float* __restrict__ gk,
                                                    const float* __restrict__ fc,
                                                    const float* __restrict__ fs) {
    __shared__ float partial[4];
    const int s = blockIdx.x;
    const int which = blockIdx.y;
    short* x = which ? g_k : g_q;
    const float* g = which ? gk : gq;
    const int tid = threadIdx.x;
    const int d0 = tid * 8;

    s8v xv = *reinterpret_cast<const s8v*>(&x[(size_t)s * DIMC + d0]);
    float xf[8];
    float ssq = 0.0f;
    for (int j = 0; j < 8; ++j) { xf[j] = b2f(xv[j]); ssq += xf[j] * xf[j]; }
    for (int off = 32; off; off >>= 1) ssq += __shfl_down(ssq, off);
    if ((tid & 63) == 0) partial[tid >> 6] = ssq;
    __syncthreads();
    float tot = partial[0] + partial[1] + partial[2] + partial[3];
    float rs = rsqrtf(tot * (1.0f / (float)DIMC) + 1e-5f);
    if (which == 0) rs *= 0.12751744f;   // log2(e)/sqrt(128)

    f4v g0 = *reinterpret_cast<const f4v*>(&g[d0]);
    f4v g1 = *reinterpret_cast<const f4v*>(&g[d0 + 4]);
    float xn[8];
    for (int j = 0; j < 4; ++j) { xn[j] = xf[j] * rs * g0[j]; xn[4 + j] = xf[4 + j] * rs * g1[j]; }

    s8v ov;
    for (int p = 0; p < 4; ++p) {
        int e = d0 + 2 * p;
        int hd = e & (DHD - 1);
        float c = fc[(size_t)s * DHD + hd];
        float sn = fs[(size_t)s * DHD + hd + 1];
        float x1 = xn[2 * p], x2 = xn[2 * p + 1];
        ov[2 * p]     = f2b(x1 * c - x2 * sn);
        ov[2 * p + 1] = f2b(x1 * sn + x2 * c);
    }
    *reinterpret_cast<s8v*>(&x[(size_t)s * DIMC + d0]) = ov;
}

// ---------------- V transpose: g_v [s][h*128+d] -> g_vt [h*128+d][s] ---------
__global__ __launch_bounds__(256) void transpose_v() {
    __shared__ __attribute__((aligned(16))) short t[64][64];
    const int h = blockIdx.z, dt = blockIdx.y, st = blockIdx.x;
    const int tid = threadIdx.x;
    const short* src = g_v + (size_t)st * 64 * DIMC + h * DHD + dt * 64;
    for (int i = 0; i < 2; ++i) {
        int slot = tid + i * 256;
        int s = slot >> 3, db = slot & 7;
        int pb = (db + (s >> 3)) & 7;                       // rotated phys block
        *reinterpret_cast<s8v*>(&t[s][pb * 8]) =
            *reinterpret_cast<const s8v*>(src + (size_t)s * DIMC + db * 8);
    }
    __syncthreads();
    short* dst = g_vt + (size_t)(h * DHD + dt * 64) * SEQ + st * 64;
    for (int i = 0; i < 2; ++i) {
        int slot = tid + i * 256;
        int d = slot >> 3, sb = (slot & 7) * 8;
        int pb = ((d >> 3) + (slot & 7)) & 7;               // row>>3 == slot&7 for all j
        s8v o;
        for (int j = 0; j < 8; ++j) o[j] = t[sb + j][pb * 8 + (d & 7)];
        *reinterpret_cast<s8v*>(dst + (size_t)d * SEQ + sb) = o;
    }
}

// ---------------- flash attention, 32x32 MFMA, in-register softmax (T12) -----
// Dual-chain ILP version (verified r6: 146.6 us, MfmaUtil 48, VALU 31).
__global__ __launch_bounds__(256, 2) void attn_k() {
    __shared__ __attribute__((aligned(16))) short Ks0[2][64 * 128];   // [buf][key][dh], cb rotated by key
    __shared__ __attribute__((aligned(16))) short Vt0[2][128 * 64];   // [buf][dh][key], kb rotated by dh

    const int h = blockIdx.y;
    const int q0 = blockIdx.x * 128;
    const int tid = threadIdx.x;
    const int w = tid >> 6, lane = tid & 63;
    const int l32 = lane & 31, hf = lane >> 5;
    const int l16 = lane & 15;
    const int cbase = hf + l16;        // K read: cs = (dc*2 + cbase) & 15
    const int khl = hf + l32;          // V read: ks = (kc*4 + kp2*2 + khl) & 7

    // Q B-frags: qf[dc] = Q[q = q0+w*32+l32][d = dc*16 + hf*8 .. +7]
    bf8 qf[8];
    {
        const short* qb = g_q + (size_t)(q0 + w * 32 + l32) * DIMC + h * DHD + hf * 8;
#pragma unroll
        for (int dc = 0; dc < 8; ++dc)
            qf[dc] = *reinterpret_cast<const bf8*>(qb + dc * 16);
    }

    f16v of[4];
#pragma unroll
    for (int i = 0; i < 4; ++i) of[i] = (f16v)0.0f;
    f16v lacc = (f16v)0.0f;
    const f16v fz = (f16v)0.0f;

    s8v ob;
#pragma unroll
    for (int j = 0; j < 8; ++j) ob[j] = (short)0x3F80;   // bf16 1.0
    const bf8 vones = __builtin_bit_cast(bf8, ob);

    const short* Kbase = g_k + h * DHD;
    const short* Vbase = g_vt + (size_t)h * DHD * SEQ;

    const short* kp[4];
    const short* vp[4];
#pragma unroll
    for (int i = 0; i < 4; ++i) {
        int s = tid + i * 256;
        int krow = s >> 4, kcb = ((s & 15) - krow) & 15;   // rotated global cb
        int vd = s >> 3, vkb = ((s & 7) - vd) & 7;         // rotated global kb
        kp[i] = Kbase + (size_t)krow * DIMC + kcb * 8;
        vp[i] = Vbase + (size_t)vd * SEQ + vkb * 8;
    }

    // prologue: stage tile 0 into buffer 0 (8 loads in flight)
#pragma unroll
    for (int i = 0; i < 4; ++i) {
        gl_lds16(kp[i], &Ks0[0][(size_t)(i * 256 + w * 64) * 8]);
        kp[i] += (size_t)64 * DIMC;
    }
#pragma unroll
    for (int i = 0; i < 4; ++i) {
        gl_lds16(vp[i], &Vt0[0][(size_t)(i * 256 + w * 64) * 8]);
        vp[i] += 64;
    }

    auto softmax_pack = [&](const f16v& sa, bf8& paA, bf8& paB) {
        int wv[8];
#pragma unroll
        for (int t = 0; t < 8; ++t)
            wv[t] = pk2b(fexp2(sa[2 * t]), fexp2(sa[2 * t + 1]));
        int a0 = wv[0], b0 = wv[2]; plane32_swap(a0, b0);
        int a1 = wv[1], b1 = wv[3]; plane32_swap(a1, b1);
        int a2 = wv[4], b2 = wv[6]; plane32_swap(a2, b2);
        int a3 = wv[5], b3 = wv[7]; plane32_swap(a3, b3);
        i4v p0 = {a0, a1, b0, b1};
        i4v p1 = {a2, a3, b2, b3};
        paA = __builtin_bit_cast(bf8, p0);
        paB = __builtin_bit_cast(bf8, p1);
    };

    for (int kt = 0; kt < SEQ; kt += 64) {
        const int cur = (kt >> 6) & 1;
        if (kt + 64 < SEQ) {
            const int nxt = cur ^ 1;
#pragma unroll
            for (int i = 0; i < 4; ++i) {
                gl_lds16(kp[i], &Ks0[nxt][(size_t)(i * 256 + w * 64) * 8]);
                kp[i] += (size_t)64 * DIMC;
            }
#pragma unroll
            for (int i = 0; i < 4; ++i) {
                gl_lds16(vp[i], &Vt0[nxt][(size_t)(i * 256 + w * 64) * 8]);
                vp[i] += 64;
            }
            asm volatile("s_waitcnt vmcnt(8)" ::: "memory");
        } else {
            asm volatile("s_waitcnt vmcnt(0)" ::: "memory");
        }
        __builtin_amdgcn_sched_barrier(0);
        __builtin_amdgcn_s_barrier();   // all waves' tile-t loads landed
        __builtin_amdgcn_sched_barrier(0);

        const short* Ks = Ks0[cur];
        const short* Vt = Vt0[cur];

        // ---- dual swapped QK^T: sa0/sa1 = K.Q^T for key halves 0/1
        const short* krb0 = Ks + l32 * 128;
        const short* krb1 = Ks + (32 + l32) * 128;
        f16v sa0, sa1;
        {
            bf8 k0 = *reinterpret_cast<const bf8*>(krb0 + ((cbase & 15) << 3));
            bf8 k1 = *reinterpret_cast<const bf8*>(krb1 + ((cbase & 15) << 3));
            sa0 = mfma32(k0, qf[0], fz);
            sa1 = mfma32(k1, qf[0], fz);
        }
#pragma unroll
        for (int dc = 1; dc < 8; ++dc) {
            const int cs = ((dc * 2 + cbase) & 15) << 3;
            bf8 k0 = *reinterpret_cast<const bf8*>(krb0 + cs);
            sa0 = mfma32(k0, qf[dc], sa0);
            bf8 k1 = *reinterpret_cast<const bf8*>(krb1 + cs);
            sa1 = mfma32(k1, qf[dc], sa1);
        }

        // ---- half 0: softmax (overlaps sa1's MFMA tail) + lacc + PV
        bf8 p00, p01;
        softmax_pack(sa0, p00, p01);
        lacc = mfma32(p00, vones, lacc);
        lacc = mfma32(p01, vones, lacc);
#pragma unroll
        for (int kp2 = 0; kp2 < 2; ++kp2) {
            bf8 pa = kp2 ? p01 : p00;
#pragma unroll
            for (int dcb = 0; dcb < 4; ++dcb) {
                bf8 vf = *reinterpret_cast<const bf8*>(
                    Vt + (dcb * 32 + l32) * 64 + (((kp2 * 2 + khl) & 7) << 3));
                of[dcb] = mfma32(pa, vf, of[dcb]);
            }
        }

        // ---- half 1: softmax (overlaps PV0's MFMAs) + lacc + PV
        bf8 p10, p11;
        softmax_pack(sa1, p10, p11);
        lacc = mfma32(p10, vones, lacc);
        lacc = mfma32(p11, vones, lacc);
#pragma unroll
        for (int kp2 = 0; kp2 < 2; ++kp2) {
            bf8 pa = kp2 ? p11 : p10;
#pragma unroll
            for (int dcb = 0; dcb < 4; ++dcb) {
                bf8 vf = *reinterpret_cast<const bf8*>(
                    Vt + (dcb * 32 + l32) * 64 + (((4 + kp2 * 2 + khl) & 7) << 3));
                of[dcb] = mfma32(pa, vf, of[dcb]);
            }
        }

        __builtin_amdgcn_s_barrier();   // all reads of buf[cur] done before re-stage
        __builtin_amdgcn_sched_barrier(0);
    }

    // epilogue: normalize and write back to g_q
#pragma unroll
    for (int r = 0; r < 16; ++r) {
        float iv = 1.0f / lacc[r];
        int row = q0 + w * 32 + (r & 3) + 8 * (r >> 2) + 4 * hf;
#pragma unroll
        for (int dcb = 0; dcb < 4; ++dcb)
            g_q[(size_t)row * DIMC + h * DHD + dcb * 32 + l32] = f2b(of[dcb][r] * iv);
    }
}

extern "C" void kernel_launch(void* const* d_in, const int* in_sizes, int n_in,
                              void* d_out, int out_size, void* d_ws, size_t ws_size,
                              hipStream_t stream) {
    const float* hidden = (const float*)d_in[0];
    const float* fc = (const float*)d_in[1];
    const float* fs = (const float*)d_in[2];
    const float* Wq = (const float*)d_in[3];
    const float* bq = (const float*)d_in[4];
    const float* Wk = (const float*)d_in[5];
    const float* bk = (const float*)d_in[6];
    const float* Wv = (const float*)d_in[7];
    const float* bv = (const float*)d_in[8];
    const float* Wo = (const float*)d_in[9];
    const float* bo = (const float*)d_in[10];
    const float* gq = (const float*)d_in[11];
    const float* gk = (const float*)d_in[12];

    dim3 blk(256);
    conv_h<<<dim3(4096), blk, 0, stream>>>(hidden);
    prep_w<<<dim3(32, 32, 4), blk, 0, stream>>>(Wq, Wk, Wv, Wo);
    gemm_qkv<<<dim3(16, 16, 3), dim3(512), 0, stream>>>(bq, bk, bv);
    rmsnorm_rope<<<dim3(SEQ, 2), blk, 0, stream>>>(gq, gk, fc, fs);
    transpose_v<<<dim3(64, 2, NH), blk, 0, stream>>>();
    attn_k<<<dim3(32, NH), blk, 0, stream>>>();
    gemm_o<<<dim3(16, 16), dim3(512), 0, stream>>>(bo, (float*)d_out);
}

// Round 8
// 499.065 us; speedup vs baseline: 1.1030x; 1.1030x over previous
//
#include <hip/hip_runtime.h>
#include <hip/hip_bf16.h>

#define SEQ 4096
#define DIMC 2048
#define NH 16
#define DHD 128

typedef short s8v __attribute__((ext_vector_type(8)));
typedef float f4v __attribute__((ext_vector_type(4)));
typedef __bf16 bf8 __attribute__((ext_vector_type(8)));
typedef float f4 __attribute__((ext_vector_type(4)));
typedef float f16v __attribute__((ext_vector_type(16)));
typedef int i4v __attribute__((ext_vector_type(4)));

typedef __attribute__((address_space(3))) void lds_t;
typedef __attribute__((address_space(1))) void gbl_t;

// Static device scratch (112 MiB). No d_ws dependence.
__device__ __attribute__((aligned(256))) short g_h[(size_t)SEQ * DIMC];
__device__ __attribute__((aligned(256))) short g_q[(size_t)SEQ * DIMC];
__device__ __attribute__((aligned(256))) short g_k[(size_t)SEQ * DIMC];
__device__ __attribute__((aligned(256))) short g_v[(size_t)SEQ * DIMC];
__device__ __attribute__((aligned(256))) short g_vt[(size_t)DIMC * SEQ];     // [h*128+d][s]
__device__ __attribute__((aligned(256))) short g_wt[4][(size_t)DIMC * DIMC]; // [n][k]

__device__ __forceinline__ float b2f(short s) {
    union { unsigned u; float f; } v;
    v.u = ((unsigned)(unsigned short)s) << 16;
    return v.f;
}
__device__ __forceinline__ short f2b(float f) {
    union { float f; unsigned u; } v;
    v.f = f;
    unsigned b = v.u;
    b += 0x7FFFu + ((b >> 16) & 1u);   // RNE
    return (short)(b >> 16);
}
__device__ __forceinline__ f4 mfma16(bf8 a, bf8 b, f4 c) {
    return __builtin_amdgcn_mfma_f32_16x16x32_bf16(a, b, c, 0, 0, 0);
}
__device__ __forceinline__ f16v mfma32(bf8 a, bf8 b, f16v c) {
    return __builtin_amdgcn_mfma_f32_32x32x16_bf16(a, b, c, 0, 0, 0);
}
__device__ __forceinline__ void gl_lds16(const short* g, short* l) {
    __builtin_amdgcn_global_load_lds((gbl_t*)g, (lds_t*)l, 16, 0, 0);
}
// v_permlane32_swap_b32: a' = [a_lo, b_lo], b' = [a_hi, b_hi] (32-lane halves)
__device__ __forceinline__ void plane32_swap(int& a, int& b) {
    asm("v_permlane32_swap_b32 %0, %1" : "+v"(a), "+v"(b));
}
// packed f32 pair -> one u32 of 2x bf16 (RNE), T12 recipe (no builtin on gfx950)
__device__ __forceinline__ int pk2b(float a, float b) {
    int r;
    asm("v_cvt_pk_bf16_f32 %0, %1, %2" : "=v"(r) : "v"(a), "v"(b));
    return r;
}
// raw v_exp_f32 (2^x) — skips OCML denormal fixup.
__device__ __forceinline__ float fexp2(float x) {
#if __has_builtin(__builtin_amdgcn_exp2f)
    return __builtin_amdgcn_exp2f(x);
#else
    float r;
    asm("v_exp_f32 %0, %1" : "=v"(r) : "v"(x));
    return r;
#endif
}

// ---------------- hidden f32 -> g_h bf16 ----------------
__global__ __launch_bounds__(256) void conv_h(const float* __restrict__ src) {
    size_t i = ((size_t)blockIdx.x * 256 + threadIdx.x) * 8;
    f4v u0 = *reinterpret_cast<const f4v*>(src + i);
    f4v u1 = *reinterpret_cast<const f4v*>(src + i + 4);
    s8v t;
    for (int j = 0; j < 4; ++j) { t[j] = f2b(u0[j]); t[4 + j] = f2b(u1[j]); }
    *reinterpret_cast<s8v*>(g_h + i) = t;
}

// ---------------- W f32 [k][n] -> g_wt[z] bf16 [n][k] ----------------
__global__ __launch_bounds__(256) void prep_w(const float* __restrict__ W0,
                                              const float* __restrict__ W1,
                                              const float* __restrict__ W2,
                                              const float* __restrict__ W3) {
    __shared__ __attribute__((aligned(16))) float t[64][64];
    const int z = blockIdx.z;
    const float* W = (z == 0) ? W0 : (z == 1) ? W1 : (z == 2) ? W2 : W3;
    short* WT = g_wt[z];
    const int r0 = blockIdx.y * 64, c0 = blockIdx.x * 64;   // r=k, c=n
    const int tid = threadIdx.x;
    for (int i = 0; i < 4; ++i) {
        int slot = tid + i * 256;
        int r = slot >> 4, c4 = (slot & 15) * 4;
        int pb = ((c4 >> 3) + (r >> 3)) & 7;                // rotated phys block
        *reinterpret_cast<f4v*>(&t[r][pb * 8 + (c4 & 7)]) =
            *reinterpret_cast<const f4v*>(&W[(size_t)(r0 + r) * DIMC + c0 + c4]);
    }
    __syncthreads();
    for (int i = 0; i < 2; ++i) {
        int slot = tid + i * 256;
        int n = slot >> 3, k8 = (slot & 7) * 8;
        int pb = ((n >> 3) + (slot & 7)) & 7;               // row>>3 == slot&7 for all j
        s8v o;
        for (int j = 0; j < 8; ++j) o[j] = f2b(t[k8 + j][pb * 8 + (n & 7)]);
        *reinterpret_cast<s8v*>(&WT[(size_t)(c0 + n) * DIMC + r0 + k8]) = o;
    }
}

// ---------------- pipelined GEMM: 2 phases x 16 MFMA per K-tile --------------
// BM=256, BN=128, BK=64, 512 threads = 8 waves (4M x 2N), per-wave C = 64x64.
// 3 LDS buffers (144 KiB): while computing K-tile t, stage tile t+2 —
// vmcnt(6) at each tile boundary drains only tile t+1's 6 loads (t+2's stay
// in flight; never 0 in steady state). Per K-tile: TWO phases of 16 MFMA
// each (B-frags read once in phase 0 and register-cached across the tile;
// A-frags 4 per phase) — 4 barriers/K-tile, 16 MFMA per barrier pair.
// A/B tiles stored with per-row rotated 8-bf16 chunks (phys = (g+row)&7,
// pre-rotated global source): all frag reads bank-conflict-free (verified r7).
template <int DSTF>
__device__ __forceinline__ void gemm8_body(const short* __restrict__ X,
                                           const short* __restrict__ Bw,
                                           const float* __restrict__ bias,
                                           short* __restrict__ Yb,
                                           float* __restrict__ Yf,
                                           int bm, int bn) {
    __shared__ __attribute__((aligned(16))) short Al[3][256 * 64];
    __shared__ __attribute__((aligned(16))) short Bl[3][128 * 64];
    const int tid = threadIdx.x;
    const int w = tid >> 6, lane = tid & 63;
    const int l16 = lane & 15, quad = lane >> 4;
    const int wm = w & 3, wn = w >> 2;

    // staging source (rotated chunks: phys chunk tid&7 holds global chunk gch)
    const int row0 = tid >> 3, cp0 = tid & 7;
    const int gch = (cp0 - row0) & 7;
    const short* srcA = X + (size_t)(bm * 256 + row0) * DIMC + gch * 8;
    const short* srcB = Bw + (size_t)(bn * 128 + row0) * DIMC + gch * 8;

    // loop-invariant ds_read offsets (in shorts)
    int offA[2][2][2];   // [phase][fi][kh]
    int offB[4][2];      // [ni][kh]
#pragma unroll
    for (int h = 0; h < 2; ++h)
#pragma unroll
        for (int fi = 0; fi < 2; ++fi)
#pragma unroll
            for (int kh = 0; kh < 2; ++kh) {
                int ra = wm * 64 + (h * 2 + fi) * 16 + l16;
                offA[h][fi][kh] = ra * 64 + ((((kh * 4 + quad) + ra) & 7) << 3);
            }
#pragma unroll
    for (int ni = 0; ni < 4; ++ni)
#pragma unroll
        for (int kh = 0; kh < 2; ++kh) {
            int rb = wn * 64 + ni * 16 + l16;
            offB[ni][kh] = rb * 64 + ((((kh * 4 + quad) + rb) & 7) << 3);
        }

    f4 acc[4][4];
#pragma unroll
    for (int i = 0; i < 4; ++i)
#pragma unroll
        for (int j = 0; j < 4; ++j) acc[i][j] = (f4)0.0f;

    const int NT = DIMC / 64;   // 32

    // prologue: stage tiles 0,1 (6 loads each); wait tile 0, keep tile 1 in flight
#pragma unroll
    for (int x = 0; x < 2; ++x) {
        gl_lds16(srcA,                        &Al[x][0] + tid * 8);
        gl_lds16(srcA + (size_t)64 * DIMC,    &Al[x][0] + (tid + 512) * 8);
        gl_lds16(srcA + (size_t)128 * DIMC,   &Al[x][0] + 8192 + tid * 8);
        gl_lds16(srcA + (size_t)192 * DIMC,   &Al[x][0] + 8192 + (tid + 512) * 8);
        gl_lds16(srcB,                        &Bl[x][0] + tid * 8);
        gl_lds16(srcB + (size_t)64 * DIMC,    &Bl[x][0] + (tid + 512) * 8);
        srcA += 64; srcB += 64;
    }
    asm volatile("s_waitcnt vmcnt(6)" ::: "memory");
    __builtin_amdgcn_sched_barrier(0);
    __builtin_amdgcn_s_barrier();

    int b = 0;
    for (int t = 0; t < NT; ++t) {
        const short* Ab = &Al[b][0];
        const short* Bb = &Bl[b][0];
        const int sb = (b + 2 >= 3) ? b - 1 : b + 2;
        short* dA = &Al[sb][0];
        short* dB = &Bl[sb][0];
        const bool doStage = (t + 2 < NT);

        // ================= phase 0: B(all)+A(rows 0,1), 16 MFMA ==============
        bf8 bv[4][2];
#pragma unroll
        for (int ni = 0; ni < 4; ++ni)
#pragma unroll
            for (int kh = 0; kh < 2; ++kh)
                bv[ni][kh] = *reinterpret_cast<const bf8*>(Bb + offB[ni][kh]);
        bf8 av[2][2];
#pragma unroll
        for (int fi = 0; fi < 2; ++fi)
#pragma unroll
            for (int kh = 0; kh < 2; ++kh)
                av[fi][kh] = *reinterpret_cast<const bf8*>(Ab + offA[0][fi][kh]);
        if (doStage) {
            gl_lds16(srcA,                      dA + tid * 8);
            gl_lds16(srcA + (size_t)64 * DIMC,  dA + (tid + 512) * 8);
            gl_lds16(srcB,                      dB + tid * 8);
        }
        __builtin_amdgcn_s_barrier();
        asm volatile("s_waitcnt lgkmcnt(0)" ::: "memory");
        __builtin_amdgcn_sched_barrier(0);
        __builtin_amdgcn_s_setprio(1);
#pragma unroll
        for (int fi = 0; fi < 2; ++fi)
#pragma unroll
            for (int ni = 0; ni < 4; ++ni) {
                acc[fi][ni] = mfma16(av[fi][0], bv[ni][0], acc[fi][ni]);
                acc[fi][ni] = mfma16(av[fi][1], bv[ni][1], acc[fi][ni]);
            }
        __builtin_amdgcn_s_setprio(0);
        __builtin_amdgcn_s_barrier();

        // ================= phase 1: A(rows 2,3), 16 MFMA =====================
#pragma unroll
        for (int fi = 0; fi < 2; ++fi)
#pragma unroll
            for (int kh = 0; kh < 2; ++kh)
                av[fi][kh] = *reinterpret_cast<const bf8*>(Ab + offA[1][fi][kh]);
        if (doStage) {
            gl_lds16(srcA + (size_t)128 * DIMC, dA + 8192 + tid * 8);
            gl_lds16(srcA + (size_t)192 * DIMC, dA + 8192 + (tid + 512) * 8);
            gl_lds16(srcB + (size_t)64 * DIMC,  dB + (tid + 512) * 8);
        }
        __builtin_amdgcn_s_barrier();
        asm volatile("s_waitcnt lgkmcnt(0)" ::: "memory");
        __builtin_amdgcn_sched_barrier(0);
        __builtin_amdgcn_s_setprio(1);
#pragma unroll
        for (int fi = 0; fi < 2; ++fi)
#pragma unroll
            for (int ni = 0; ni < 4; ++ni) {
                acc[2 + fi][ni] = mfma16(av[fi][0], bv[ni][0], acc[2 + fi][ni]);
                acc[2 + fi][ni] = mfma16(av[fi][1], bv[ni][1], acc[2 + fi][ni]);
            }
        __builtin_amdgcn_s_setprio(0);
        // tile boundary: drain only tile t+1's 6 loads (t+2's stay in flight)
        if (t + 1 == NT - 1) {
            asm volatile("s_waitcnt vmcnt(0)" ::: "memory");
        } else {
            asm volatile("s_waitcnt vmcnt(6)" ::: "memory");
        }
        __builtin_amdgcn_sched_barrier(0);
        __builtin_amdgcn_s_barrier();

        if (doStage) { srcA += 64; srcB += 64; }
        b = (b + 1 == 3) ? 0 : b + 1;
    }

    // epilogue: bias + store
#pragma unroll
    for (int nf = 0; nf < 4; ++nf) {
        int col = bn * 128 + wn * 64 + nf * 16 + l16;
        float bcol = bias[col];
#pragma unroll
        for (int mf = 0; mf < 4; ++mf) {
            int row = bm * 256 + wm * 64 + mf * 16 + quad * 4;
#pragma unroll
            for (int r = 0; r < 4; ++r) {
                if (DSTF)
                    Yf[(size_t)(row + r) * DIMC + col] = acc[mf][nf][r] + bcol;
                else
                    Yb[(size_t)(row + r) * DIMC + col] = f2b(acc[mf][nf][r] + bcol);
            }
        }
    }
}

__global__ __launch_bounds__(512, 2) void gemm_qkv(const float* __restrict__ bq,
                                                   const float* __restrict__ bk,
                                                   const float* __restrict__ bv) {
    const int z = blockIdx.z;
    const float* bias = (z == 0) ? bq : (z == 1) ? bk : bv;
    short* Y = (z == 0) ? g_q : (z == 1) ? g_k : g_v;
    gemm8_body<0>(g_h, g_wt[z], bias, Y, nullptr, blockIdx.y, blockIdx.x);
}

__global__ __launch_bounds__(512, 2) void gemm_o(const float* __restrict__ bias,
                                                 float* __restrict__ Yf) {
    gemm8_body<1>(g_q, g_wt[3], bias, nullptr, Yf, blockIdx.y, blockIdx.x);
}

// ---------------- fused RMSNorm + RoPE, in place on g_q/g_k ------
// q pre-scaled by log2(e)/sqrt(DHD) (folded attn scale + exp2 conversion).
__global__ __launch_bounds__(256) void rmsnorm_rope(const float* __restrict__ gq,
                                                    const float* __restrict__ gk,
                                                    const float* __restrict__ fc,
                                                    const float* __restrict__ fs) {
    __shared__ float partial[4];
    const int s = blockIdx.x;
    const int which = blockIdx.y;
    short* x = which ? g_k : g_q;
    const float* g = which ? gk : gq;
    const int tid = threadIdx.x;
    const int d0 = tid * 8;

    s8v xv = *reinterpret_cast<const s8v*>(&x[(size_t)s * DIMC + d0]);
    float xf[8];
    float ssq = 0.0f;
    for (int j = 0; j < 8; ++j) { xf[j] = b2f(xv[j]); ssq += xf[j] * xf[j]; }
    for (int off = 32; off; off >>= 1) ssq += __shfl_down(ssq, off);
    if ((tid & 63) == 0) partial[tid >> 6] = ssq;
    __syncthreads();
    float tot = partial[0] + partial[1] + partial[2] + partial[3];
    float rs = rsqrtf(tot * (1.0f / (float)DIMC) + 1e-5f);
    if (which == 0) rs *= 0.12751744f;   // log2(e)/sqrt(128)

    f4v g0 = *reinterpret_cast<const f4v*>(&g[d0]);
    f4v g1 = *reinterpret_cast<const f4v*>(&g[d0 + 4]);
    float xn[8];
    for (int j = 0; j < 4; ++j) { xn[j] = xf[j] * rs * g0[j]; xn[4 + j] = xf[4 + j] * rs * g1[j]; }

    s8v ov;
    for (int p = 0; p < 4; ++p) {
        int e = d0 + 2 * p;
        int hd = e & (DHD - 1);
        float c = fc[(size_t)s * DHD + hd];
        float sn = fs[(size_t)s * DHD + hd + 1];
        float x1 = xn[2 * p], x2 = xn[2 * p + 1];
        ov[2 * p]     = f2b(x1 * c - x2 * sn);
        ov[2 * p + 1] = f2b(x1 * sn + x2 * c);
    }
    *reinterpret_cast<s8v*>(&x[(size_t)s * DIMC + d0]) = ov;
}

// ---------------- V transpose: g_v [s][h*128+d] -> g_vt [h*128+d][s] ---------
__global__ __launch_bounds__(256) void transpose_v() {
    __shared__ __attribute__((aligned(16))) short t[64][64];
    const int h = blockIdx.z, dt = blockIdx.y, st = blockIdx.x;
    const int tid = threadIdx.x;
    const short* src = g_v + (size_t)st * 64 * DIMC + h * DHD + dt * 64;
    for (int i = 0; i < 2; ++i) {
        int slot = tid + i * 256;
        int s = slot >> 3, db = slot & 7;
        int pb = (db + (s >> 3)) & 7;                       // rotated phys block
        *reinterpret_cast<s8v*>(&t[s][pb * 8]) =
            *reinterpret_cast<const s8v*>(src + (size_t)s * DIMC + db * 8);
    }
    __syncthreads();
    short* dst = g_vt + (size_t)(h * DHD + dt * 64) * SEQ + st * 64;
    for (int i = 0; i < 2; ++i) {
        int slot = tid + i * 256;
        int d = slot >> 3, sb = (slot & 7) * 8;
        int pb = ((d >> 3) + (slot & 7)) & 7;               // row>>3 == slot&7 for all j
        s8v o;
        for (int j = 0; j < 8; ++j) o[j] = t[sb + j][pb * 8 + (d & 7)];
        *reinterpret_cast<s8v*>(dst + (size_t)d * SEQ + sb) = o;
    }
}

// ---------------- flash attention, 32x32 MFMA, in-register softmax (T12) -----
// Dual-chain ILP version (verified r6: 146.6 us, MfmaUtil 48, VALU 31).
__global__ __launch_bounds__(256, 2) void attn_k() {
    __shared__ __attribute__((aligned(16))) short Ks0[2][64 * 128];   // [buf][key][dh], cb rotated by key
    __shared__ __attribute__((aligned(16))) short Vt0[2][128 * 64];   // [buf][dh][key], kb rotated by dh

    const int h = blockIdx.y;
    const int q0 = blockIdx.x * 128;
    const int tid = threadIdx.x;
    const int w = tid >> 6, lane = tid & 63;
    const int l32 = lane & 31, hf = lane >> 5;
    const int l16 = lane & 15;
    const int cbase = hf + l16;        // K read: cs = (dc*2 + cbase) & 15
    const int khl = hf + l32;          // V read: ks = (kc*4 + kp2*2 + khl) & 7

    // Q B-frags: qf[dc] = Q[q = q0+w*32+l32][d = dc*16 + hf*8 .. +7]
    bf8 qf[8];
    {
        const short* qb = g_q + (size_t)(q0 + w * 32 + l32) * DIMC + h * DHD + hf * 8;
#pragma unroll
        for (int dc = 0; dc < 8; ++dc)
            qf[dc] = *reinterpret_cast<const bf8*>(qb + dc * 16);
    }

    f16v of[4];
#pragma unroll
    for (int i = 0; i < 4; ++i) of[i] = (f16v)0.0f;
    f16v lacc = (f16v)0.0f;
    const f16v fz = (f16v)0.0f;

    s8v ob;
#pragma unroll
    for (int j = 0; j < 8; ++j) ob[j] = (short)0x3F80;   // bf16 1.0
    const bf8 vones = __builtin_bit_cast(bf8, ob);

    const short* Kbase = g_k + h * DHD;
    const short* Vbase = g_vt + (size_t)h * DHD * SEQ;

    const short* kp[4];
    const short* vp[4];
#pragma unroll
    for (int i = 0; i < 4; ++i) {
        int s = tid + i * 256;
        int krow = s >> 4, kcb = ((s & 15) - krow) & 15;   // rotated global cb
        int vd = s >> 3, vkb = ((s & 7) - vd) & 7;         // rotated global kb
        kp[i] = Kbase + (size_t)krow * DIMC + kcb * 8;
        vp[i] = Vbase + (size_t)vd * SEQ + vkb * 8;
    }

    // prologue: stage tile 0 into buffer 0 (8 loads in flight)
#pragma unroll
    for (int i = 0; i < 4; ++i) {
        gl_lds16(kp[i], &Ks0[0][(size_t)(i * 256 + w * 64) * 8]);
        kp[i] += (size_t)64 * DIMC;
    }
#pragma unroll
    for (int i = 0; i < 4; ++i) {
        gl_lds16(vp[i], &Vt0[0][(size_t)(i * 256 + w * 64) * 8]);
        vp[i] += 64;
    }

    auto softmax_pack = [&](const f16v& sa, bf8& paA, bf8& paB) {
        int wv[8];
#pragma unroll
        for (int t = 0; t < 8; ++t)
            wv[t] = pk2b(fexp2(sa[2 * t]), fexp2(sa[2 * t + 1]));
        int a0 = wv[0], b0 = wv[2]; plane32_swap(a0, b0);
        int a1 = wv[1], b1 = wv[3]; plane32_swap(a1, b1);
        int a2 = wv[4], b2 = wv[6]; plane32_swap(a2, b2);
        int a3 = wv[5], b3 = wv[7]; plane32_swap(a3, b3);
        i4v p0 = {a0, a1, b0, b1};
        i4v p1 = {a2, a3, b2, b3};
        paA = __builtin_bit_cast(bf8, p0);
        paB = __builtin_bit_cast(bf8, p1);
    };

    for (int kt = 0; kt < SEQ; kt += 64) {
        const int cur = (kt >> 6) & 1;
        if (kt + 64 < SEQ) {
            const int nxt = cur ^ 1;
#pragma unroll
            for (int i = 0; i < 4; ++i) {
                gl_lds16(kp[i], &Ks0[nxt][(size_t)(i * 256 + w * 64) * 8]);
                kp[i] += (size_t)64 * DIMC;
            }
#pragma unroll
            for (int i = 0; i < 4; ++i) {
                gl_lds16(vp[i], &Vt0[nxt][(size_t)(i * 256 + w * 64) * 8]);
                vp[i] += 64;
            }
            asm volatile("s_waitcnt vmcnt(8)" ::: "memory");
        } else {
            asm volatile("s_waitcnt vmcnt(0)" ::: "memory");
        }
        __builtin_amdgcn_sched_barrier(0);
        __builtin_amdgcn_s_barrier();   // all waves' tile-t loads landed
        __builtin_amdgcn_sched_barrier(0);

        const short* Ks = Ks0[cur];
        const short* Vt = Vt0[cur];

        // ---- dual swapped QK^T: sa0/sa1 = K.Q^T for key halves 0/1
        const short* krb0 = Ks + l32 * 128;
        const short* krb1 = Ks + (32 + l32) * 128;
        f16v sa0, sa1;
        {
            bf8 k0 = *reinterpret_cast<const bf8*>(krb0 + ((cbase & 15) << 3));
            bf8 k1 = *reinterpret_cast<const bf8*>(krb1 + ((cbase & 15) << 3));
            sa0 = mfma32(k0, qf[0], fz);
            sa1 = mfma32(k1, qf[0], fz);
        }
#pragma unroll
        for (int dc = 1; dc < 8; ++dc) {
            const int cs = ((dc * 2 + cbase) & 15) << 3;
            bf8 k0 = *reinterpret_cast<const bf8*>(krb0 + cs);
            sa0 = mfma32(k0, qf[dc], sa0);
            bf8 k1 = *reinterpret_cast<const bf8*>(krb1 + cs);
            sa1 = mfma32(k1, qf[dc], sa1);
        }

        // ---- half 0: softmax (overlaps sa1's MFMA tail) + lacc + PV
        bf8 p00, p01;
        softmax_pack(sa0, p00, p01);
        lacc = mfma32(p00, vones, lacc);
        lacc = mfma32(p01, vones, lacc);
#pragma unroll
        for (int kp2 = 0; kp2 < 2; ++kp2) {
            bf8 pa = kp2 ? p01 : p00;
#pragma unroll
            for (int dcb = 0; dcb < 4; ++dcb) {
                bf8 vf = *reinterpret_cast<const bf8*>(
                    Vt + (dcb * 32 + l32) * 64 + (((kp2 * 2 + khl) & 7) << 3));
                of[dcb] = mfma32(pa, vf, of[dcb]);
            }
        }

        // ---- half 1: softmax (overlaps PV0's MFMAs) + lacc + PV
        bf8 p10, p11;
        softmax_pack(sa1, p10, p11);
        lacc = mfma32(p10, vones, lacc);
        lacc = mfma32(p11, vones, lacc);
#pragma unroll
        for (int kp2 = 0; kp2 < 2; ++kp2) {
            bf8 pa = kp2 ? p11 : p10;
#pragma unroll
            for (int dcb = 0; dcb < 4; ++dcb) {
                bf8 vf = *reinterpret_cast<const bf8*>(
                    Vt + (dcb * 32 + l32) * 64 + (((4 + kp2 * 2 + khl) & 7) << 3));
                of[dcb] = mfma32(pa, vf, of[dcb]);
            }
        }

        __builtin_amdgcn_s_barrier();   // all reads of buf[cur] done before re-stage
        __builtin_amdgcn_sched_barrier(0);
    }

    // epilogue: normalize and write back to g_q
#pragma unroll
    for (int r = 0; r < 16; ++r) {
        float iv = 1.0f / lacc[r];
        int row = q0 + w * 32 + (r & 3) + 8 * (r >> 2) + 4 * hf;
#pragma unroll
        for (int dcb = 0; dcb < 4; ++dcb)
            g_q[(size_t)row * DIMC + h * DHD + dcb * 32 + l32] = f2b(of[dcb][r] * iv);
    }
}

extern "C" void kernel_launch(void* const* d_in, const int* in_sizes, int n_in,
                              void* d_out, int out_size, void* d_ws, size_t ws_size,
                              hipStream_t stream) {
    const float* hidden = (const float*)d_in[0];
    const float* fc = (const float*)d_in[1];
    const float* fs = (const float*)d_in[2];
    const float* Wq = (const float*)d_in[3];
    const float* bq = (const float*)d_in[4];
    const float* Wk = (const float*)d_in[5];
    const float* bk = (const float*)d_in[6];
    const float* Wv = (const float*)d_in[7];
    const float* bv = (const float*)d_in[8];
    const float* Wo = (const float*)d_in[9];
    const float* bo = (const float*)d_in[10];
    const float* gq = (const float*)d_in[11];
    const float* gk = (const float*)d_in[12];

    dim3 blk(256);
    conv_h<<<dim3(4096), blk, 0, stream>>>(hidden);
    prep_w<<<dim3(32, 32, 4), blk, 0, stream>>>(Wq, Wk, Wv, Wo);
    gemm_qkv<<<dim3(16, 16, 3), dim3(512), 0, stream>>>(bq, bk, bv);
    rmsnorm_rope<<<dim3(SEQ, 2), blk, 0, stream>>>(gq, gk, fc, fs);
    transpose_v<<<dim3(64, 2, NH), blk, 0, stream>>>();
    attn_k<<<dim3(32, NH), blk, 0, stream>>>();
    gemm_o<<<dim3(16, 16), dim3(512), 0, stream>>>(bo, (float*)d_out);
}